// Round 1
// baseline (21337.300 us; speedup 1.0000x reference)
//
#include <hip/hip_runtime.h>

typedef _Float16 half8 __attribute__((ext_vector_type(8)));
typedef float f32x4 __attribute__((ext_vector_type(4)));

#define GRIDN 192
#define NTICKS 514
#define TT 512
#define HH 1024

__device__ __forceinline__ int kfrag(int l, int j) {
  // consistent A/B fragment k mapping (two K=16 halves, 4-element chunks per 16-lane group)
  return ((j >> 2) << 4) + (((l >> 4) & 3) << 2) + (j & 3);
}

__device__ __forceinline__ size_t fragoff(int m, int k, int KBv) {
  int rt = m >> 4, mm = m & 15, kb = k >> 5, kk = k & 31;
  int lp = mm | ((kk & 12) << 2);           // lane'
  int jp = ((kk >> 4) << 2) | (kk & 3);     // elem'
  return ((size_t)(rt * KBv + kb) * 512) + (size_t)lp * 8 + jp;
}

__device__ __forceinline__ float sigmoidf_(float x) { return 1.0f / (1.0f + __expf(-x)); }
__device__ __forceinline__ float tanhf_(float x)    { return 2.0f / (1.0f + __expf(-2.0f * x)) - 1.0f; }

// ---------------- weight pack: W[k][4096] -> frag layout [cg][kb][gate][lane*8+j] (f16) ---------
__global__ __launch_bounds__(256) void pack_b_kernel(const float* __restrict__ W,
                                                     _Float16* __restrict__ dst, int KB) {
  int e = blockIdx.x * 256 + threadIdx.x;
  int total = 64 * KB * 4 * 512;
  if (e >= total) return;
  int j = e & 7, l = (e >> 3) & 63, nt = (e >> 9) & 3;
  int tmp = e >> 11;
  int kb = tmp % KB, cg = tmp / KB;
  int k = kb * 32 + kfrag(l, j);
  int col = nt * 1024 + cg * 16 + (l & 15);
  dst[e] = (_Float16)W[(size_t)k * 4096 + col];
}

// ---------------- x pack: struct[b][t][d] -> frag layout [t][rt][kb][lane*8+j] (f16) ------------
__global__ __launch_bounds__(256) void pack_x_kernel(const float* __restrict__ x,
                                                     _Float16* __restrict__ dst) {
  int e = blockIdx.x * 256 + threadIdx.x;
  if (e >= TT * 4 * 8 * 512) return;
  int j = e & 7, l = (e >> 3) & 63;
  int tmp = e >> 9;
  int kb = tmp & 7; tmp >>= 3;
  int rt = tmp & 3; int t = tmp >> 2;
  int b = rt * 16 + (l & 15);
  int d = kb * 32 + kfrag(l, j);
  dst[e] = (_Float16)x[((size_t)b * TT + t) * 256 + d];
}

// ---------------- persistent pipelined 3-cell LSTM ----------------------------------------------
__global__ __launch_bounds__(256, 1) void lstm_coop(
    const _Float16* __restrict__ Bf1, const _Float16* __restrict__ Bf2,
    const _Float16* __restrict__ Bf3, const _Float16* __restrict__ Ax,
    _Float16* A1h, _Float16* A2v, _Float16* A3v,
    float* c1, float* h1, float* c2, float* h2, float* c3, float* h3,
    const float* __restrict__ bb1, const float* __restrict__ bb2, const float* __restrict__ bb3,
    unsigned* bar) {
  __shared__ float red[4][16][64][4];   // 64 KiB: [warp][rt*4+nt][lane][reg]

  const int cell = blockIdx.x >> 6;     // 0,1,2
  const int cg   = blockIdx.x & 63;     // column group: 16 h-cols
  const int warp = threadIdx.x >> 6;
  const int lane = threadIdx.x & 63;

  const int KB  = (cell == 0) ? 40 : 64;          // K blocks of 32
  const int AKB = (cell == 0) ? 32 : 64;          // K blocks in own A array
  const int kb0 = (cell == 0) ? warp * 10 : warp * 16;
  const int kb1 = (cell == 0) ? kb0 + 10 : kb0 + 16;

  const _Float16* Bf = (cell == 0) ? Bf1 : (cell == 1) ? Bf2 : Bf3;
  const _Float16* Bbase = Bf + (size_t)cg * KB * 4 * 512 + (size_t)lane * 8;

  _Float16* Aown  = (cell == 0) ? A1h : (cell == 1) ? A2v : A3v;
  _Float16* Anext = (cell == 0) ? A2v : (cell == 1) ? A3v : nullptr;

  float* cst = (cell == 0) ? c1 : (cell == 1) ? c2 : c3;
  float* hst = (cell == 0) ? h1 : (cell == 1) ? h2 : h3;
  const float* bias = (cell == 0) ? bb1 : (cell == 1) ? bb2 : bb3;

  const int hcol = cg * 16 + (lane & 15);
  float bv[4];
#pragma unroll
  for (int nt = 0; nt < 4; ++nt) bv[nt] = bias[nt * HH + hcol];

  for (int tick = 0; tick < NTICKS; ++tick) {
    const int t = tick - cell;
    if (t >= 0 && t < TT) {
      const int wpar = tick & 1, rpar = wpar ^ 1;
      f32x4 acc[4][4];
#pragma unroll
      for (int a = 0; a < 4; ++a)
#pragma unroll
        for (int b2 = 0; b2 < 4; ++b2) acc[a][b2] = (f32x4){0.f, 0.f, 0.f, 0.f};

      const _Float16* Ard = Aown + (size_t)rpar * 4 * AKB * 512 + (size_t)lane * 8;

      for (int kb = kb0; kb < kb1; ++kb) {
        half8 av[4], bw[4];
        if (cell == 0 && kb >= 32) {
          const _Float16* Axb = Ax + ((size_t)t * 4 * 8 + (kb - 32)) * 512 + (size_t)lane * 8;
#pragma unroll
          for (int rt = 0; rt < 4; ++rt) av[rt] = *(const half8*)(Axb + (size_t)rt * 8 * 512);
        } else {
#pragma unroll
          for (int rt = 0; rt < 4; ++rt) av[rt] = *(const half8*)(Ard + ((size_t)rt * AKB + kb) * 512);
        }
        const _Float16* Bk = Bbase + (size_t)kb * 4 * 512;
#pragma unroll
        for (int nt = 0; nt < 4; ++nt) bw[nt] = *(const half8*)(Bk + (size_t)nt * 512);
#pragma unroll
        for (int rt = 0; rt < 4; ++rt)
#pragma unroll
          for (int nt = 0; nt < 4; ++nt)
            acc[rt][nt] = __builtin_amdgcn_mfma_f32_16x16x32_f16(av[rt], bw[nt], acc[rt][nt], 0, 0, 0);
      }

      // K-split reduction across the 4 warps via LDS
#pragma unroll
      for (int rt = 0; rt < 4; ++rt)
#pragma unroll
        for (int nt = 0; nt < 4; ++nt)
          *(f32x4*)&red[warp][rt * 4 + nt][lane][0] = acc[rt][nt];
      __syncthreads();

      f32x4 sv[4];
#pragma unroll
      for (int nt = 0; nt < 4; ++nt) {
        f32x4 s = *(f32x4*)&red[0][warp * 4 + nt][lane][0];
#pragma unroll
        for (int w2 = 1; w2 < 4; ++w2) s += *(f32x4*)&red[w2][warp * 4 + nt][lane][0];
        sv[nt] = s;
      }

      // elementwise: this warp owns rows m in [16*warp, 16*warp+16)
#pragma unroll
      for (int r = 0; r < 4; ++r) {
        float fv = sv[0][r] + bv[0];
        float iv = sv[1][r] + bv[1];
        float ov = sv[2][r] + bv[2];
        float gv = sv[3][r] + bv[3];
        int m = warp * 16 + ((lane >> 4) << 2) + r;
        int sidx = m * HH + hcol;
        float sf = sigmoidf_(fv), si = sigmoidf_(iv), so = sigmoidf_(ov);
        float tg = tanhf_(gv);
        float c_old = cst[sidx], h_old = hst[sidx];
        float c0 = sf * c_old + si * tg;
        float h0 = so * tanhf_(c0);
        float cn = 0.9f * c0 + 0.1f * c_old;
        float hn = 0.9f * h0 + 0.1f * h_old;
        cst[sidx] = cn;
        hst[sidx] = hn;
        _Float16 hv = (_Float16)hn;
        Aown[(size_t)wpar * 4 * AKB * 512 + fragoff(m, hcol, AKB)] = hv;
        if (cell < 2) Anext[(size_t)wpar * 4 * 64 * 512 + fragoff(m, 1024 + hcol, 64)] = hv;
      }
    }

    // grid barrier (device-scope, sense via monotonically increasing generation)
    __syncthreads();
    if (threadIdx.x == 0) {
      __threadfence();
      unsigned arrived = __hip_atomic_fetch_add(&bar[0], 1u, __ATOMIC_ACQ_REL, __HIP_MEMORY_SCOPE_AGENT);
      if (arrived == GRIDN - 1) {
        __hip_atomic_store(&bar[0], 0u, __ATOMIC_RELAXED, __HIP_MEMORY_SCOPE_AGENT);
        __hip_atomic_fetch_add(&bar[16], 1u, __ATOMIC_RELEASE, __HIP_MEMORY_SCOPE_AGENT);
      } else {
        while (__hip_atomic_load(&bar[16], __ATOMIC_ACQUIRE, __HIP_MEMORY_SCOPE_AGENT) <
               (unsigned)(tick + 1)) {
          __builtin_amdgcn_s_sleep(2);
        }
      }
    }
    __syncthreads();
  }
}

// ---------------- final FC + ELU: out[b][c] = elu(h3[b,:]·fc_w[c,:] + fc_b[c]) ------------------
__global__ __launch_bounds__(256) void fc_kernel(const float* __restrict__ h3,
                                                 const float* __restrict__ fcw,
                                                 const float* __restrict__ fcb,
                                                 float* __restrict__ out) {
  int wid = (blockIdx.x * 256 + threadIdx.x) >> 6;
  int lane = threadIdx.x & 63;
  if (wid >= 64 * 128) return;
  int b = wid >> 7, cc = wid & 127;
  float s = 0.f;
#pragma unroll
  for (int i = 0; i < 16; ++i) {
    int k = i * 64 + lane;
    s += h3[b * HH + k] * fcw[cc * HH + k];
  }
#pragma unroll
  for (int o = 32; o; o >>= 1) s += __shfl_xor(s, o, 64);
  if (lane == 0) {
    s += fcb[cc];
    out[b * 128 + cc] = s > 0.f ? s : (__expf(s) - 1.0f);
  }
}

extern "C" void kernel_launch(void* const* d_in, const int* in_sizes, int n_in,
                              void* d_out, int out_size, void* d_ws, size_t ws_size,
                              hipStream_t stream) {
  const float* xs  = (const float*)d_in[0];
  const float* W1  = (const float*)d_in[1];
  const float* b1  = (const float*)d_in[2];
  const float* W2  = (const float*)d_in[3];
  const float* b2  = (const float*)d_in[4];
  const float* W3  = (const float*)d_in[5];
  const float* b3  = (const float*)d_in[6];
  const float* fcw = (const float*)d_in[7];
  const float* fcb = (const float*)d_in[8];
  float* out = (float*)d_out;

  char* p = (char*)d_ws;
  auto alloc = [&](size_t bytes) {
    char* r = p;
    p += (bytes + 255) & ~(size_t)255;
    return r;
  };

  // ---- zero-init region (re-zeroed every replay) ----
  char* zbase = p;
  _Float16* A1h = (_Float16*)alloc((size_t)2 * 4 * 32 * 512 * 2);
  _Float16* A2v = (_Float16*)alloc((size_t)2 * 4 * 64 * 512 * 2);
  _Float16* A3v = (_Float16*)alloc((size_t)2 * 4 * 64 * 512 * 2);
  float* c1 = (float*)alloc((size_t)64 * 1024 * 4);
  float* h1 = (float*)alloc((size_t)64 * 1024 * 4);
  float* c2 = (float*)alloc((size_t)64 * 1024 * 4);
  float* h2 = (float*)alloc((size_t)64 * 1024 * 4);
  float* c3 = (float*)alloc((size_t)64 * 1024 * 4);
  float* h3 = (float*)alloc((size_t)64 * 1024 * 4);
  unsigned* bar = (unsigned*)alloc(256);
  size_t zbytes = (size_t)(p - zbase);

  // ---- fully-overwritten region ----
  _Float16* Bf1 = (_Float16*)alloc((size_t)64 * 40 * 4 * 512 * 2);
  _Float16* Bf2 = (_Float16*)alloc((size_t)64 * 64 * 4 * 512 * 2);
  _Float16* Bf3 = (_Float16*)alloc((size_t)64 * 64 * 4 * 512 * 2);
  _Float16* Axp = (_Float16*)alloc((size_t)TT * 4 * 8 * 512 * 2);

  hipMemsetAsync(zbase, 0, zbytes, stream);

  {
    int tot1 = 64 * 40 * 4 * 512, tot23 = 64 * 64 * 4 * 512;
    pack_b_kernel<<<(tot1 + 255) / 256, 256, 0, stream>>>(W1, Bf1, 40);
    pack_b_kernel<<<(tot23 + 255) / 256, 256, 0, stream>>>(W2, Bf2, 64);
    pack_b_kernel<<<(tot23 + 255) / 256, 256, 0, stream>>>(W3, Bf3, 64);
    int totx = TT * 4 * 8 * 512;
    pack_x_kernel<<<(totx + 255) / 256, 256, 0, stream>>>(xs, Axp);
  }

  lstm_coop<<<GRIDN, 256, 0, stream>>>(Bf1, Bf2, Bf3, Axp, A1h, A2v, A3v,
                                       c1, h1, c2, h2, c3, h3, b1, b2, b3, bar);

  fc_kernel<<<(64 * 128 * 64 + 255) / 256, 256, 0, stream>>>(h3, fcw, fcb, out);
}

// Round 3
// 15197.083 us; speedup vs baseline: 1.4040x; 1.4040x over previous
//
#include <hip/hip_runtime.h>

typedef _Float16 half8 __attribute__((ext_vector_type(8)));
typedef float f32x4 __attribute__((ext_vector_type(4)));

#define GRIDN 192
#define NTICKS 514
#define TT 512
#define HH 1024

__device__ __forceinline__ int kfrag(int l, int j) {
  // consistent A/B fragment k mapping (two K=16 halves, 4-element chunks per 16-lane group)
  return ((j >> 2) << 4) + (((l >> 4) & 3) << 2) + (j & 3);
}

__device__ __forceinline__ size_t fragoff(int m, int k, int KBv) {
  int rt = m >> 4, mm = m & 15, kb = k >> 5, kk = k & 31;
  int lp = mm | ((kk & 12) << 2);           // lane'
  int jp = ((kk >> 4) << 2) | (kk & 3);     // elem'
  return ((size_t)(rt * KBv + kb) * 512) + (size_t)lp * 8 + jp;
}

__device__ __forceinline__ float sigmoidf_(float x) { return 1.0f / (1.0f + __expf(-x)); }
__device__ __forceinline__ float tanhf_(float x)    { return 2.0f / (1.0f + __expf(-2.0f * x)) - 1.0f; }

// ---------------- weight pack: W[k][4096] -> frag layout [cg][kb][gate][lane*8+j] (f16) ---------
__global__ __launch_bounds__(256) void pack_b_kernel(const float* __restrict__ W,
                                                     _Float16* __restrict__ dst, int KB) {
  int e = blockIdx.x * 256 + threadIdx.x;
  int total = 64 * KB * 4 * 512;
  if (e >= total) return;
  int j = e & 7, l = (e >> 3) & 63, nt = (e >> 9) & 3;
  int tmp = e >> 11;
  int kb = tmp % KB, cg = tmp / KB;
  int k = kb * 32 + kfrag(l, j);
  int col = nt * 1024 + cg * 16 + (l & 15);
  dst[e] = (_Float16)W[(size_t)k * 4096 + col];
}

// ---------------- x pack: struct[b][t][d] -> frag layout [t][rt][kb][lane*8+j] (f16) ------------
__global__ __launch_bounds__(256) void pack_x_kernel(const float* __restrict__ x,
                                                     _Float16* __restrict__ dst) {
  int e = blockIdx.x * 256 + threadIdx.x;
  if (e >= TT * 4 * 8 * 512) return;
  int j = e & 7, l = (e >> 3) & 63;
  int tmp = e >> 9;
  int kb = tmp & 7; tmp >>= 3;
  int rt = tmp & 3; int t = tmp >> 2;
  int b = rt * 16 + (l & 15);
  int d = kb * 32 + kfrag(l, j);
  dst[e] = (_Float16)x[((size_t)b * TT + t) * 256 + d];
}

// ---------------- grid barrier: 8 padded monotonic counters, leaderless ------------------------
__device__ __forceinline__ void grid_barrier(unsigned* bar, int tick) {
  __syncthreads();
  if (threadIdx.x == 0) {
    __threadfence();  // release: wbl2 — publish this block's A-frag stores device-wide
    __hip_atomic_fetch_add(&bar[32 * (blockIdx.x & 7)], 1u, __ATOMIC_RELAXED,
                           __HIP_MEMORY_SCOPE_AGENT);
  }
  if (threadIdx.x < 64) {
    const unsigned target = (unsigned)(tick + 1) * 24u;  // 192/8 arrivals per counter per tick
    const int lane = threadIdx.x;
    for (;;) {
      unsigned v = target;
      if (lane < 8)
        v = __hip_atomic_load(&bar[32 * lane], __ATOMIC_RELAXED, __HIP_MEMORY_SCOPE_AGENT);
      if (__all(v >= target)) break;
      __builtin_amdgcn_s_sleep(2);
    }
    __threadfence();  // acquire: inv — drop stale A lines from this XCD's L2 (once per tick)
  }
  __syncthreads();
}

// ---------------- persistent pipelined cell loop (weights register-resident) --------------------
template <int CELL, int KBW, int AKB>
__device__ __forceinline__ void run_cell(float (*red)[16][64][4],
                                         const _Float16* __restrict__ Bf,
                                         const _Float16* __restrict__ Ax,
                                         _Float16* Aown, _Float16* Anext,
                                         const float* __restrict__ bias,
                                         float* __restrict__ h3out, unsigned* bar) {
  const int cg   = blockIdx.x & 63;
  const int warp = threadIdx.x >> 6;
  const int lane = threadIdx.x & 63;
  const int KBTOT = (CELL == 0) ? 40 : 64;
  const int kb0   = warp * KBW;
  const int hcol  = cg * 16 + (lane & 15);

  float bv[4];
#pragma unroll
  for (int nt = 0; nt < 4; ++nt) bv[nt] = bias[nt * HH + hcol];

  // ---- preload this warp's weight slice into registers (loop-invariant) ----
  half8 w[KBW][4];
  const _Float16* Bbase = Bf + (size_t)cg * KBTOT * 4 * 512 + (size_t)lane * 8;
#pragma unroll
  for (int kk = 0; kk < KBW; ++kk)
#pragma unroll
    for (int nt = 0; nt < 4; ++nt)
      w[kk][nt] = *(const half8*)(Bbase + ((size_t)(kb0 + kk) * 4 + nt) * 512);

  // ---- persistent cell state in registers: lane owns 4 (row,col) pairs ----
  f32x4 creg = (f32x4){0.f, 0.f, 0.f, 0.f};
  f32x4 hreg = (f32x4){0.f, 0.f, 0.f, 0.f};

  for (int tick = 0; tick < NTICKS; ++tick) {
    const int t = tick - CELL;
    if (t >= 0 && t < TT) {
      const int wpar = tick & 1, rpar = wpar ^ 1;
      const _Float16* Ard = Aown + (size_t)rpar * 4 * AKB * 512 + (size_t)lane * 8;
      const _Float16* Axt = Ax + (size_t)t * 4 * 8 * 512 + (size_t)lane * 8;

      auto aptr = [&](int kk, int rt) -> const _Float16* {
        int kb = kb0 + kk;
        if (CELL == 0 && kb >= 32) return Axt + ((size_t)rt * 8 + (kb - 32)) * 512;
        return Ard + ((size_t)rt * AKB + kb) * 512;
      };

      // 3-deep A prefetch pipeline (ring of 4, all indices compile-time)
      half8 av[4][4];
#pragma unroll
      for (int p = 0; p < 3; ++p)
#pragma unroll
        for (int rt = 0; rt < 4; ++rt) av[p][rt] = *(const half8*)aptr(p, rt);

      f32x4 acc[4][4];
#pragma unroll
      for (int a = 0; a < 4; ++a)
#pragma unroll
        for (int b2 = 0; b2 < 4; ++b2) acc[a][b2] = (f32x4){0.f, 0.f, 0.f, 0.f};

#pragma unroll
      for (int kk = 0; kk < KBW; ++kk) {
        if (kk + 3 < KBW) {
#pragma unroll
          for (int rt = 0; rt < 4; ++rt)
            av[(kk + 3) & 3][rt] = *(const half8*)aptr(kk + 3, rt);
        }
#pragma unroll
        for (int rt = 0; rt < 4; ++rt)
#pragma unroll
          for (int nt = 0; nt < 4; ++nt)
            acc[rt][nt] = __builtin_amdgcn_mfma_f32_16x16x32_f16(av[kk & 3][rt], w[kk][nt],
                                                                 acc[rt][nt], 0, 0, 0);
      }

      // K-split reduction across the 4 warps via LDS
#pragma unroll
      for (int rt = 0; rt < 4; ++rt)
#pragma unroll
        for (int nt = 0; nt < 4; ++nt)
          *(f32x4*)&red[warp][rt * 4 + nt][lane][0] = acc[rt][nt];
      __syncthreads();

      f32x4 sv[4];
#pragma unroll
      for (int nt = 0; nt < 4; ++nt) {
        f32x4 s = *(f32x4*)&red[0][warp * 4 + nt][lane][0];
#pragma unroll
        for (int w2 = 1; w2 < 4; ++w2) s += *(f32x4*)&red[w2][warp * 4 + nt][lane][0];
        sv[nt] = s;
      }

      // elementwise: this warp owns rows m in [16*warp, 16*warp+16), state in registers
#pragma unroll
      for (int r = 0; r < 4; ++r) {
        float fv = sv[0][r] + bv[0];
        float iv = sv[1][r] + bv[1];
        float ov = sv[2][r] + bv[2];
        float gv = sv[3][r] + bv[3];
        int m = warp * 16 + ((lane >> 4) << 2) + r;
        float sf = sigmoidf_(fv), si = sigmoidf_(iv), so = sigmoidf_(ov);
        float tg = tanhf_(gv);
        float c_old = creg[r], h_old = hreg[r];
        float c0 = sf * c_old + si * tg;
        float h0 = so * tanhf_(c0);
        float cn = 0.9f * c0 + 0.1f * c_old;
        float hn = 0.9f * h0 + 0.1f * h_old;
        creg[r] = cn;
        hreg[r] = hn;
        _Float16 hv = (_Float16)hn;
        Aown[(size_t)wpar * 4 * AKB * 512 + fragoff(m, hcol, AKB)] = hv;
        if (CELL < 2) Anext[(size_t)wpar * 4 * 64 * 512 + fragoff(m, 1024 + hcol, 64)] = hv;
        if (CELL == 2 && t == TT - 1) h3out[m * HH + hcol] = hn;
      }
    }

    if (tick < NTICKS - 1) grid_barrier(bar, tick);
  }
}

__global__ __launch_bounds__(256, 1) void lstm_coop(
    const _Float16* __restrict__ Bf1, const _Float16* __restrict__ Bf2,
    const _Float16* __restrict__ Bf3, const _Float16* __restrict__ Ax,
    _Float16* A1h, _Float16* A2v, _Float16* A3v, float* h3,
    const float* __restrict__ bb1, const float* __restrict__ bb2, const float* __restrict__ bb3,
    unsigned* bar) {
  __shared__ float red[4][16][64][4];  // single 64 KiB buffer, shared by all three cell paths
  const int cell = blockIdx.x >> 6;
  if (cell == 0)
    run_cell<0, 10, 32>(red, Bf1, Ax, A1h, A2v, bb1, nullptr, bar);
  else if (cell == 1)
    run_cell<1, 16, 64>(red, Bf2, Ax, A2v, A3v, bb2, nullptr, bar);
  else
    run_cell<2, 16, 64>(red, Bf3, Ax, A3v, nullptr, bb3, h3, bar);
}

// ---------------- final FC + ELU: out[b][c] = elu(h3[b,:]·fc_w[c,:] + fc_b[c]) ------------------
__global__ __launch_bounds__(256) void fc_kernel(const float* __restrict__ h3,
                                                 const float* __restrict__ fcw,
                                                 const float* __restrict__ fcb,
                                                 float* __restrict__ out) {
  int wid = (blockIdx.x * 256 + threadIdx.x) >> 6;
  int lane = threadIdx.x & 63;
  if (wid >= 64 * 128) return;
  int b = wid >> 7, cc = wid & 127;
  float s = 0.f;
#pragma unroll
  for (int i = 0; i < 16; ++i) {
    int k = i * 64 + lane;
    s += h3[b * HH + k] * fcw[cc * HH + k];
  }
#pragma unroll
  for (int o = 32; o; o >>= 1) s += __shfl_xor(s, o, 64);
  if (lane == 0) {
    s += fcb[cc];
    out[b * 128 + cc] = s > 0.f ? s : (__expf(s) - 1.0f);
  }
}

extern "C" void kernel_launch(void* const* d_in, const int* in_sizes, int n_in,
                              void* d_out, int out_size, void* d_ws, size_t ws_size,
                              hipStream_t stream) {
  const float* xs  = (const float*)d_in[0];
  const float* W1  = (const float*)d_in[1];
  const float* b1  = (const float*)d_in[2];
  const float* W2  = (const float*)d_in[3];
  const float* b2  = (const float*)d_in[4];
  const float* W3  = (const float*)d_in[5];
  const float* b3  = (const float*)d_in[6];
  const float* fcw = (const float*)d_in[7];
  const float* fcb = (const float*)d_in[8];
  float* out = (float*)d_out;

  char* p = (char*)d_ws;
  auto alloc = [&](size_t bytes) {
    char* r = p;
    p += (bytes + 255) & ~(size_t)255;
    return r;
  };

  // ---- zero-init region (re-zeroed every replay) ----
  char* zbase = p;
  _Float16* A1h = (_Float16*)alloc((size_t)2 * 4 * 32 * 512 * 2);
  _Float16* A2v = (_Float16*)alloc((size_t)2 * 4 * 64 * 512 * 2);
  _Float16* A3v = (_Float16*)alloc((size_t)2 * 4 * 64 * 512 * 2);
  unsigned* bar = (unsigned*)alloc(1024);
  size_t zbytes = (size_t)(p - zbase);

  // ---- fully-overwritten region ----
  float* h3 = (float*)alloc((size_t)64 * 1024 * 4);
  _Float16* Bf1 = (_Float16*)alloc((size_t)64 * 40 * 4 * 512 * 2);
  _Float16* Bf2 = (_Float16*)alloc((size_t)64 * 64 * 4 * 512 * 2);
  _Float16* Bf3 = (_Float16*)alloc((size_t)64 * 64 * 4 * 512 * 2);
  _Float16* Axp = (_Float16*)alloc((size_t)TT * 4 * 8 * 512 * 2);

  (void)hipMemsetAsync(zbase, 0, zbytes, stream);

  {
    int tot1 = 64 * 40 * 4 * 512, tot23 = 64 * 64 * 4 * 512;
    pack_b_kernel<<<(tot1 + 255) / 256, 256, 0, stream>>>(W1, Bf1, 40);
    pack_b_kernel<<<(tot23 + 255) / 256, 256, 0, stream>>>(W2, Bf2, 64);
    pack_b_kernel<<<(tot23 + 255) / 256, 256, 0, stream>>>(W3, Bf3, 64);
    int totx = TT * 4 * 8 * 512;
    pack_x_kernel<<<(totx + 255) / 256, 256, 0, stream>>>(xs, Axp);
  }

  lstm_coop<<<GRIDN, 256, 0, stream>>>(Bf1, Bf2, Bf3, Axp, A1h, A2v, A3v, h3,
                                       b1, b2, b3, bar);

  fc_kernel<<<(64 * 128 * 64 + 255) / 256, 256, 0, stream>>>(h3, fcw, fcb, out);
}

// Round 4
// 10035.857 us; speedup vs baseline: 2.1261x; 1.5143x over previous
//
#include <hip/hip_runtime.h>

typedef _Float16 half8 __attribute__((ext_vector_type(8)));
typedef float f32x4 __attribute__((ext_vector_type(4)));

#define GRIDN 192
#define NTICKS 514
#define TT 512
#define HH 1024

// MFMA with B operand pinned in AGPRs (gfx950 unified RF: MFMA reads A/B from AGPR).
// "a" constraint forces the weight live-range into the accumulator file, where the
// per-tick buffer_inv (acquire fence) cannot evict it and regalloc cannot remat loads.
#define MFMA_F16_AB(acc_, a_, b_) \
  asm("v_mfma_f32_16x16x32_f16 %0, %1, %2, %0" : "+v"(acc_) : "v"(a_), "a"(b_))

__device__ __forceinline__ int kfrag(int l, int j) {
  // consistent A/B fragment k mapping (two K=16 halves, 4-element chunks per 16-lane group)
  return ((j >> 2) << 4) + (((l >> 4) & 3) << 2) + (j & 3);
}

__device__ __forceinline__ size_t fragoff(int m, int k, int KBv) {
  int rt = m >> 4, mm = m & 15, kb = k >> 5, kk = k & 31;
  int lp = mm | ((kk & 12) << 2);           // lane'
  int jp = ((kk >> 4) << 2) | (kk & 3);     // elem'
  return ((size_t)(rt * KBv + kb) * 512) + (size_t)lp * 8 + jp;
}

__device__ __forceinline__ float sigmoidf_(float x) { return 1.0f / (1.0f + __expf(-x)); }
__device__ __forceinline__ float tanhf_(float x)    { return 2.0f / (1.0f + __expf(-2.0f * x)) - 1.0f; }

// ---------------- weight pack: W[k][4096] -> frag layout [cg][kb][gate][lane*8+j] (f16) ---------
__global__ __launch_bounds__(256) void pack_b_kernel(const float* __restrict__ W,
                                                     _Float16* __restrict__ dst, int KB) {
  int e = blockIdx.x * 256 + threadIdx.x;
  int total = 64 * KB * 4 * 512;
  if (e >= total) return;
  int j = e & 7, l = (e >> 3) & 63, nt = (e >> 9) & 3;
  int tmp = e >> 11;
  int kb = tmp % KB, cg = tmp / KB;
  int k = kb * 32 + kfrag(l, j);
  int col = nt * 1024 + cg * 16 + (l & 15);
  dst[e] = (_Float16)W[(size_t)k * 4096 + col];
}

// ---------------- x pack: struct[b][t][d] -> frag layout [t][rt][kb][lane*8+j] (f16) ------------
__global__ __launch_bounds__(256) void pack_x_kernel(const float* __restrict__ x,
                                                     _Float16* __restrict__ dst) {
  int e = blockIdx.x * 256 + threadIdx.x;
  if (e >= TT * 4 * 8 * 512) return;
  int j = e & 7, l = (e >> 3) & 63;
  int tmp = e >> 9;
  int kb = tmp & 7; tmp >>= 3;
  int rt = tmp & 3; int t = tmp >> 2;
  int b = rt * 16 + (l & 15);
  int d = kb * 32 + kfrag(l, j);
  dst[e] = (_Float16)x[((size_t)b * TT + t) * 256 + d];
}

// ---------------- grid barrier: 8 padded monotonic counters, leaderless ------------------------
__device__ __forceinline__ void grid_barrier(unsigned* bar, int tick) {
  __syncthreads();
  if (threadIdx.x == 0) {
    __threadfence();  // release: publish this block's A-frag stores device-wide
    __hip_atomic_fetch_add(&bar[32 * (blockIdx.x & 7)], 1u, __ATOMIC_RELAXED,
                           __HIP_MEMORY_SCOPE_AGENT);
  }
  if (threadIdx.x < 64) {
    const unsigned target = (unsigned)(tick + 1) * 24u;  // 192/8 arrivals per counter per tick
    const int lane = threadIdx.x;
    for (;;) {
      unsigned v = target;
      if (lane < 8)
        v = __hip_atomic_load(&bar[32 * lane], __ATOMIC_RELAXED, __HIP_MEMORY_SCOPE_AGENT);
      if (__all(v >= target)) break;
      __builtin_amdgcn_s_sleep(2);
    }
    __threadfence();  // acquire: inv — drop stale A lines from this XCD's L2 (once per tick)
  }
  __syncthreads();
}

// ---------------- persistent pipelined cell loop (weights AGPR-resident) ------------------------
template <int CELL, int KBW, int AKB>
__device__ __forceinline__ void run_cell(float (*red)[16][64][4],
                                         const _Float16* __restrict__ Bf,
                                         const _Float16* __restrict__ Ax,
                                         _Float16* Aown, _Float16* Anext,
                                         const float* __restrict__ bias,
                                         float* __restrict__ h3out, unsigned* bar) {
  const int cg   = blockIdx.x & 63;
  const int warp = threadIdx.x >> 6;
  const int lane = threadIdx.x & 63;
  const int KBTOT = (CELL == 0) ? 40 : 64;
  const int kb0   = warp * KBW;
  const int hcol  = cg * 16 + (lane & 15);

  float bv[4];
#pragma unroll
  for (int nt = 0; nt < 4; ++nt) bv[nt] = bias[nt * HH + hcol];

  // ---- preload this warp's weight slice; "a"-constrained uses pin it in AGPRs ----
  half8 w[KBW][4];
  const _Float16* Bbase = Bf + (size_t)cg * KBTOT * 4 * 512 + (size_t)lane * 8;
#pragma unroll
  for (int kk = 0; kk < KBW; ++kk)
#pragma unroll
    for (int nt = 0; nt < 4; ++nt)
      w[kk][nt] = *(const half8*)(Bbase + ((size_t)(kb0 + kk) * 4 + nt) * 512);

  // ---- persistent cell state in registers: lane owns 4 (row,col) pairs ----
  f32x4 creg = (f32x4){0.f, 0.f, 0.f, 0.f};
  f32x4 hreg = (f32x4){0.f, 0.f, 0.f, 0.f};

  for (int tick = 0; tick < NTICKS; ++tick) {
    const int t = tick - CELL;
    if (t >= 0 && t < TT) {
      const int wpar = tick & 1, rpar = wpar ^ 1;
      const _Float16* Ard = Aown + (size_t)rpar * 4 * AKB * 512 + (size_t)lane * 8;
      const _Float16* Axt = Ax + (size_t)t * 4 * 8 * 512 + (size_t)lane * 8;

      auto aptr = [&](int kk, int rt) -> const _Float16* {
        int kb = kb0 + kk;
        if (CELL == 0 && kb >= 32) return Axt + ((size_t)rt * 8 + (kb - 32)) * 512;
        return Ard + ((size_t)rt * AKB + kb) * 512;
      };

      // 3-deep A prefetch pipeline (ring of 4, all indices compile-time)
      half8 av[4][4];
#pragma unroll
      for (int p = 0; p < 3; ++p)
#pragma unroll
        for (int rt = 0; rt < 4; ++rt) av[p][rt] = *(const half8*)aptr(p, rt);

      f32x4 acc[4][4];
#pragma unroll
      for (int a = 0; a < 4; ++a)
#pragma unroll
        for (int b2 = 0; b2 < 4; ++b2) acc[a][b2] = (f32x4){0.f, 0.f, 0.f, 0.f};

#pragma unroll
      for (int kk = 0; kk < KBW; ++kk) {
        if (kk + 3 < KBW) {
#pragma unroll
          for (int rt = 0; rt < 4; ++rt)
            av[(kk + 3) & 3][rt] = *(const half8*)aptr(kk + 3, rt);
        }
#pragma unroll
        for (int rt = 0; rt < 4; ++rt)
#pragma unroll
          for (int nt = 0; nt < 4; ++nt)
            MFMA_F16_AB(acc[rt][nt], av[kk & 3][rt], w[kk][nt]);
      }
      // guard asm-MFMA -> VALU/DS read-after-write (hazard recognizer can't see into asm)
      asm volatile("s_nop 7\n\ts_nop 7");

      // K-split reduction across the 4 warps via LDS
#pragma unroll
      for (int rt = 0; rt < 4; ++rt)
#pragma unroll
        for (int nt = 0; nt < 4; ++nt)
          *(f32x4*)&red[warp][rt * 4 + nt][lane][0] = acc[rt][nt];
      __syncthreads();

      f32x4 sv[4];
#pragma unroll
      for (int nt = 0; nt < 4; ++nt) {
        f32x4 s = *(f32x4*)&red[0][warp * 4 + nt][lane][0];
#pragma unroll
        for (int w2 = 1; w2 < 4; ++w2) s += *(f32x4*)&red[w2][warp * 4 + nt][lane][0];
        sv[nt] = s;
      }

      // elementwise: this warp owns rows m in [16*warp, 16*warp+16), state in registers
#pragma unroll
      for (int r = 0; r < 4; ++r) {
        float fv = sv[0][r] + bv[0];
        float iv = sv[1][r] + bv[1];
        float ov = sv[2][r] + bv[2];
        float gv = sv[3][r] + bv[3];
        int m = warp * 16 + ((lane >> 4) << 2) + r;
        float sf = sigmoidf_(fv), si = sigmoidf_(iv), so = sigmoidf_(ov);
        float tg = tanhf_(gv);
        float c_old = creg[r], h_old = hreg[r];
        float c0 = sf * c_old + si * tg;
        float h0 = so * tanhf_(c0);
        float cn = 0.9f * c0 + 0.1f * c_old;
        float hn = 0.9f * h0 + 0.1f * h_old;
        creg[r] = cn;
        hreg[r] = hn;
        _Float16 hv = (_Float16)hn;
        Aown[(size_t)wpar * 4 * AKB * 512 + fragoff(m, hcol, AKB)] = hv;
        if (CELL < 2) Anext[(size_t)wpar * 4 * 64 * 512 + fragoff(m, 1024 + hcol, 64)] = hv;
        if (CELL == 2 && t == TT - 1) h3out[m * HH + hcol] = hn;
      }
    }

    if (tick < NTICKS - 1) grid_barrier(bar, tick);
  }
}

__global__ __launch_bounds__(256, 1) void lstm_coop(
    const _Float16* __restrict__ Bf1, const _Float16* __restrict__ Bf2,
    const _Float16* __restrict__ Bf3, const _Float16* __restrict__ Ax,
    _Float16* A1h, _Float16* A2v, _Float16* A3v, float* h3,
    const float* __restrict__ bb1, const float* __restrict__ bb2, const float* __restrict__ bb3,
    unsigned* bar) {
  __shared__ float red[4][16][64][4];  // single 64 KiB buffer, shared by all three cell paths
  const int cell = blockIdx.x >> 6;
  if (cell == 0)
    run_cell<0, 10, 32>(red, Bf1, Ax, A1h, A2v, bb1, nullptr, bar);
  else if (cell == 1)
    run_cell<1, 16, 64>(red, Bf2, Ax, A2v, A3v, bb2, nullptr, bar);
  else
    run_cell<2, 16, 64>(red, Bf3, Ax, A3v, nullptr, bb3, h3, bar);
}

// ---------------- final FC + ELU: out[b][c] = elu(h3[b,:]·fc_w[c,:] + fc_b[c]) ------------------
__global__ __launch_bounds__(256) void fc_kernel(const float* __restrict__ h3,
                                                 const float* __restrict__ fcw,
                                                 const float* __restrict__ fcb,
                                                 float* __restrict__ out) {
  int wid = (blockIdx.x * 256 + threadIdx.x) >> 6;
  int lane = threadIdx.x & 63;
  if (wid >= 64 * 128) return;
  int b = wid >> 7, cc = wid & 127;
  float s = 0.f;
#pragma unroll
  for (int i = 0; i < 16; ++i) {
    int k = i * 64 + lane;
    s += h3[b * HH + k] * fcw[cc * HH + k];
  }
#pragma unroll
  for (int o = 32; o; o >>= 1) s += __shfl_xor(s, o, 64);
  if (lane == 0) {
    s += fcb[cc];
    out[b * 128 + cc] = s > 0.f ? s : (__expf(s) - 1.0f);
  }
}

extern "C" void kernel_launch(void* const* d_in, const int* in_sizes, int n_in,
                              void* d_out, int out_size, void* d_ws, size_t ws_size,
                              hipStream_t stream) {
  const float* xs  = (const float*)d_in[0];
  const float* W1  = (const float*)d_in[1];
  const float* b1  = (const float*)d_in[2];
  const float* W2  = (const float*)d_in[3];
  const float* b2  = (const float*)d_in[4];
  const float* W3  = (const float*)d_in[5];
  const float* b3  = (const float*)d_in[6];
  const float* fcw = (const float*)d_in[7];
  const float* fcb = (const float*)d_in[8];
  float* out = (float*)d_out;

  char* p = (char*)d_ws;
  auto alloc = [&](size_t bytes) {
    char* r = p;
    p += (bytes + 255) & ~(size_t)255;
    return r;
  };

  // ---- zero-init region (re-zeroed every replay) ----
  char* zbase = p;
  _Float16* A1h = (_Float16*)alloc((size_t)2 * 4 * 32 * 512 * 2);
  _Float16* A2v = (_Float16*)alloc((size_t)2 * 4 * 64 * 512 * 2);
  _Float16* A3v = (_Float16*)alloc((size_t)2 * 4 * 64 * 512 * 2);
  unsigned* bar = (unsigned*)alloc(1024);
  size_t zbytes = (size_t)(p - zbase);

  // ---- fully-overwritten region ----
  float* h3 = (float*)alloc((size_t)64 * 1024 * 4);
  _Float16* Bf1 = (_Float16*)alloc((size_t)64 * 40 * 4 * 512 * 2);
  _Float16* Bf2 = (_Float16*)alloc((size_t)64 * 64 * 4 * 512 * 2);
  _Float16* Bf3 = (_Float16*)alloc((size_t)64 * 64 * 4 * 512 * 2);
  _Float16* Axp = (_Float16*)alloc((size_t)TT * 4 * 8 * 512 * 2);

  (void)hipMemsetAsync(zbase, 0, zbytes, stream);

  {
    int tot1 = 64 * 40 * 4 * 512, tot23 = 64 * 64 * 4 * 512;
    pack_b_kernel<<<(tot1 + 255) / 256, 256, 0, stream>>>(W1, Bf1, 40);
    pack_b_kernel<<<(tot23 + 255) / 256, 256, 0, stream>>>(W2, Bf2, 64);
    pack_b_kernel<<<(tot23 + 255) / 256, 256, 0, stream>>>(W3, Bf3, 64);
    int totx = TT * 4 * 8 * 512;
    pack_x_kernel<<<(totx + 255) / 256, 256, 0, stream>>>(xs, Axp);
  }

  lstm_coop<<<GRIDN, 256, 0, stream>>>(Bf1, Bf2, Bf3, Axp, A1h, A2v, A3v, h3,
                                       b1, b2, b3, bar);

  fc_kernel<<<(64 * 128 * 64 + 255) / 256, 256, 0, stream>>>(h3, fcw, fcb, out);
}